// Round 9
// baseline (293.428 us; speedup 1.0000x reference)
//
#include <hip/hip_runtime.h>
#include <hip/hip_bf16.h>
#include <math.h>

typedef unsigned short u16;
typedef unsigned int u32;
typedef unsigned char u8;

#define T_TOK 43904   // 128 windows * 343 tokens
#define NTOK 343
#define LOG2E 1.4426950408889634f
#define MASKV 144.26950408889634f   // 100 * log2(e)

typedef __attribute__((ext_vector_type(4))) float f32x4;
typedef __attribute__((ext_vector_type(8))) short s16x8;

__device__ __forceinline__ float bf2f(u32 v) { return __uint_as_float(v << 16); }
__device__ __forceinline__ u16 f2bf(float f) {
  u32 u = __float_as_uint(f);
  return (u16)((u + 0x7fffu + ((u >> 16) & 1u)) >> 16);
}

// ---- dual-dtype helpers: f32!=0 -> buffer is fp32, else packed bf16 ----
__device__ __forceinline__ float ldf(const void* p, int f32, size_t i) {
  return f32 ? ((const float*)p)[i] : bf2f(((const u16*)p)[i]);
}
__device__ __forceinline__ void ld8(const void* p, int f32, size_t i, float* o) {  // i%8==0
  if (f32) {
    float4 a = *(const float4*)((const float*)p + i);
    float4 b = *(const float4*)((const float*)p + i + 4);
    o[0] = a.x; o[1] = a.y; o[2] = a.z; o[3] = a.w;
    o[4] = b.x; o[5] = b.y; o[6] = b.z; o[7] = b.w;
  } else {
    uint4 pk = *(const uint4*)((const u16*)p + i);
    u32 v[4] = {pk.x, pk.y, pk.z, pk.w};
    #pragma unroll
    for (int q = 0; q < 4; q++) { o[2 * q] = bf2f(v[q] & 0xffff); o[2 * q + 1] = bf2f(v[q] >> 16); }
  }
}

// per-block dtype detection: bf16 N(0,1) never has exponent>=0x90 in its u16s;
// fp32 low mantissa halves do ~44% of the time. 512 samples -> certain.
// Every wave reads the same 512 samples -> wave-uniform result, no sync needed.
__device__ __forceinline__ int detect_f32x(const u16* xr) {
  int lane = threadIdx.x & 63;
  int bad = 0;
  #pragma unroll
  for (int q = 0; q < 8; q++) {
    u16 b = xr[(lane * 8 + q) * 2];
    if (((b >> 7) & 0xff) >= 0x90) bad = 1;
  }
  return (__ballot(bad) != 0ull) ? 1 : 0;
}

// token index t (window-major) -> element offset of the (b,d,h,w) voxel in x/out
__device__ __forceinline__ size_t spatial_base(int t) {
  int win = t / 343, n = t - win * 343;
  int bb = win >> 6, wrem = win & 63;
  int wd = wrem >> 4, wh = (wrem >> 2) & 3, ww = wrem & 3;
  int td = n / 49; int r = n - td * 49; int th = r / 7; int tw = r - th * 7;
  int d0 = wd * 7 + td + 3; if (d0 >= 28) d0 -= 28;
  int h0 = wh * 7 + th + 3; if (h0 >= 28) h0 -= 28;
  int w0 = ww * 7 + tw + 3; if (w0 >= 28) w0 -= 28;
  return (size_t)(((bb * 28 + d0) * 28 + h0) * 28 + w0) * 96;
}

// shifted-window mask region id (exact reproduction of MONAI compute_mask)
__device__ __forceinline__ int zone3(int p) { return p < 21 ? 0 : (p < 25 ? 1 : 2); }
__device__ __forceinline__ int cid_of(int mw, int n) {
  int td = n / 49, rr = n - td * 49, th = rr / 7, tw = rr - th * 7;
  int d = (mw >> 4) * 7 + td, h = ((mw >> 2) & 3) * 7 + th, w = (mw & 3) * 7 + tw;
  return zone3(d) * 9 + zone3(h) * 3 + zone3(w);
}

// ---------------- setup: weight conversion + B3M expansion ----------------
// blocks 0..431: wcat[g] = bf16(weights)   (qkv 27648 | proj 9216 | fc1 36864 | fc2 36864)
// blocks 432..774: row = b-432; b3m[cls*3+head][row][col] = (bias+mask)*log2e
__global__ __launch_bounds__(256) void setup_kernel(
    const u16* __restrict__ x,
    const void* __restrict__ w0, const void* __restrict__ w1,
    const void* __restrict__ w2, const void* __restrict__ w3,
    const void* __restrict__ bias_table, const int* __restrict__ rel,
    u16* __restrict__ wcat, u16* __restrict__ b3m) {
  int f32 = detect_f32x(x);
  int b = blockIdx.x;
  if (b < 432) {
    int g = b * 256 + threadIdx.x;
    if (g < 110592) {
      float v;
      if (g < 27648)      v = ldf(w0, f32, g);
      else if (g < 36864) v = ldf(w1, f32, g - 27648);
      else if (g < 73728) v = ldf(w2, f32, g - 36864);
      else                v = ldf(w3, f32, g - 73728);
      wcat[g] = f2bf(v);
    }
    return;
  }
  int row = b - 432;   // 0..342
  for (int by = 0; by < 24; by++) {
    int cls = by / 3, head = by - cls * 3;
    int mw = ((cls & 4) ? 48 : 0) | ((cls & 2) ? 12 : 0) | ((cls & 1) ? 3 : 0);
    int cidq = cid_of(mw, row);
    for (int col = threadIdx.x; col < 352; col += 256) {
      float v = -MASKV;
      if (col < 343) {
        v = ldf(bias_table, f32, (size_t)rel[row * 343 + col] * 3 + head) * LOG2E;
        if (cid_of(mw, col) != cidq) v -= MASKV;
      }
      b3m[((size_t)by * 343 + row) * 352 + col] = f2bf(v);
    }
  }
}

// ---------------- fused LN1 + QKV GEMM -> planar [sel*3+head][tok][32] ----------------
// grid = (343, 3), block = 256. q-plane scaled by log2e/sqrt(32).
__global__ __launch_bounds__(256) void qkv_ln_kernel(
    const void* __restrict__ x, const void* __restrict__ g1, const void* __restrict__ b1,
    const u16* __restrict__ Wb, const void* __restrict__ bias,
    u16* __restrict__ outp) {
  int f32 = detect_f32x((const u16*)x);
  __shared__ alignas(16) u16 As[128 * 104];
  __shared__ alignas(16) u16 Ws[96 * 104];
  __shared__ float gld[96], bld[96];
  int tid = threadIdx.x;
  int m0 = blockIdx.x * 128, n0 = blockIdx.y * 96;
  int w = tid >> 6, lane = tid & 63, quad = lane >> 4, l16 = lane & 15;

  // stage x rows (shifted window gather) as bf16
  for (int i = tid; i < 1536; i += 256) {
    int row = i / 12, cc = (i - row * 12) * 8;
    size_t sb = spatial_base(m0 + row);
    float f[8];
    ld8(x, f32, sb + cc, f);
    uint4 pk;
    pk.x = (u32)f2bf(f[0]) | ((u32)f2bf(f[1]) << 16);
    pk.y = (u32)f2bf(f[2]) | ((u32)f2bf(f[3]) << 16);
    pk.z = (u32)f2bf(f[4]) | ((u32)f2bf(f[5]) << 16);
    pk.w = (u32)f2bf(f[6]) | ((u32)f2bf(f[7]) << 16);
    *(uint4*)&As[row * 104 + cc] = pk;
  }
  for (int i = tid; i < 1152; i += 256) {
    int row = i / 12, cc = (i - row * 12) * 8;
    *(uint4*)&Ws[row * 104 + cc] = *(const uint4*)(Wb + (size_t)(n0 + row) * 96 + cc);
  }
  if (tid < 96) { gld[tid] = ldf(g1, f32, tid); bld[tid] = ldf(b1, f32, tid); }
  __syncthreads();

  // LN in place: 2 threads per row (halves combined via shfl_xor(1))
  {
    int row = tid >> 1, half = tid & 1;
    u32* rp = (u32*)&As[row * 104] + half * 24;
    float s = 0.f, ss = 0.f;
    #pragma unroll
    for (int m = 0; m < 24; m++) {
      u32 pk = rp[m];
      float a = bf2f(pk & 0xffff), b = bf2f(pk >> 16);
      s += a + b; ss += a * a + b * b;
    }
    s += __shfl_xor(s, 1); ss += __shfl_xor(ss, 1);
    float mean = s * (1.f / 96.f);
    float var = ss * (1.f / 96.f) - mean * mean;
    float rstd = rsqrtf(var + 1e-5f);
    int cbase = half * 48;
    #pragma unroll
    for (int m = 0; m < 24; m++) {
      u32 pk = rp[m];
      float a = bf2f(pk & 0xffff), b = bf2f(pk >> 16);
      a = (a - mean) * rstd * gld[cbase + 2 * m] + bld[cbase + 2 * m];
      b = (b - mean) * rstd * gld[cbase + 2 * m + 1] + bld[cbase + 2 * m + 1];
      rp[m] = (u32)f2bf(a) | ((u32)f2bf(b) << 16);
    }
  }
  __syncthreads();

  f32x4 acc[2][6];
  #pragma unroll
  for (int i = 0; i < 2; i++)
    #pragma unroll
    for (int j = 0; j < 6; j++) acc[i][j] = (f32x4){0.f, 0.f, 0.f, 0.f};
  #pragma unroll
  for (int kc = 0; kc < 3; kc++) {
    s16x8 fa0 = *(const s16x8*)&As[(w * 32 + l16) * 104 + kc * 32 + quad * 8];
    s16x8 fa1 = *(const s16x8*)&As[(w * 32 + 16 + l16) * 104 + kc * 32 + quad * 8];
    #pragma unroll
    for (int j = 0; j < 6; j++) {
      s16x8 fb = *(const s16x8*)&Ws[(j * 16 + l16) * 104 + kc * 32 + quad * 8];
      acc[0][j] = __builtin_amdgcn_mfma_f32_16x16x32_bf16(fa0, fb, acc[0][j], 0, 0, 0);
      acc[1][j] = __builtin_amdgcn_mfma_f32_16x16x32_bf16(fa1, fb, acc[1][j], 0, 0, 0);
    }
  }
  #pragma unroll
  for (int i = 0; i < 2; i++) {
    #pragma unroll
    for (int r = 0; r < 4; r++) {
      int mm = m0 + w * 32 + i * 16 + quad * 4 + r;
      #pragma unroll
      for (int j = 0; j < 6; j++) {
        int nn = n0 + j * 16 + l16;
        float v = acc[i][j][r] + ldf(bias, f32, nn);
        int sel = nn / 96, hd = (nn - sel * 96) >> 5, cc = nn & 31;
        float scl = (sel == 0) ? 0.25504208f : 1.0f;   // log2e / sqrt(32)
        outp[((size_t)(sel * 3 + hd) * T_TOK + mm) * 32 + cc] = f2bf(v * scl);
      }
    }
  }
}

// ---------------- MFMA flash attention (unchanged from round 8) ----------------
__device__ __forceinline__ int vsw(int ch) { return ((ch >> 1) ^ (ch >> 3)) & 3; }

__global__ __launch_bounds__(512) void attn_mfma_kernel(
    const u16* __restrict__ qkv, const u16* __restrict__ b3m,
    u16* __restrict__ attnb) {
  __shared__ alignas(16) u16 Ks[352 * 32];   // idx = tok*32 + 8*((ch>>3)^(tok&3)) + (ch&7)
  __shared__ alignas(16) u16 Vt[32 * 352];   // idx = ch*352 + 8*((tok>>3)^vsw(ch)) + (tok&7)
  __shared__ alignas(16) u16 Ps[8][512];     // idx = q*32 + 8*((k32>>3)^swl(q)) + (k32&7)

  int tid = threadIdx.x;
  int wh = blockIdx.y;
  int head = wh % 3;
  int win = wh / 3;
  int mw = win & 63;
  int cls = (((mw >> 4) == 3) ? 4 : 0) | ((((mw >> 2) & 3) == 3) ? 2 : 0) | (((mw & 3) == 3) ? 1 : 0);
  int m0 = blockIdx.x * 128;
  size_t wbase = (size_t)win * NTOK;

  const u16* qplane = qkv + ((size_t)head * T_TOK + wbase) * 32;
  const u16* kplane = qkv + ((size_t)(3 + head) * T_TOK + wbase) * 32;
  const u16* vplane = qkv + ((size_t)(6 + head) * T_TOK + wbase) * 32;

  for (int i = tid; i < 1408; i += 512) {
    int tok = i >> 2, cb = i & 3;
    uint4 kv = make_uint4(0, 0, 0, 0);
    if (tok < 343) kv = *(const uint4*)(kplane + (size_t)tok * 32 + cb * 8);
    *(uint4*)&Ks[tok * 32 + 8 * (cb ^ (tok & 3))] = kv;
  }
  for (int i = tid; i < 688; i += 512) {
    int p = i >> 2, cb = (i & 3) * 8;
    int t0 = 2 * p;
    uint4 v0 = *(const uint4*)(vplane + (size_t)t0 * 32 + cb);
    uint4 v1 = make_uint4(0, 0, 0, 0);
    if (t0 + 1 < 343) v1 = *(const uint4*)(vplane + (size_t)(t0 + 1) * 32 + cb);
    u32 a0[4] = {v0.x, v0.y, v0.z, v0.w};
    u32 a1[4] = {v1.x, v1.y, v1.z, v1.w};
    int blk = t0 >> 3, tin = (t0 & 7) >> 1;
    #pragma unroll
    for (int q = 0; q < 4; q++) {
      int ch0 = cb + 2 * q;
      u32 w0v = (a0[q] & 0xffffu) | ((a1[q] & 0xffffu) << 16);
      u32 w1v = (a0[q] >> 16) | (a1[q] & 0xffff0000u);
      ((u32*)Vt)[ch0 * 176 + 4 * (blk ^ vsw(ch0)) + tin] = w0v;
      ((u32*)Vt)[(ch0 + 1) * 176 + 4 * (blk ^ vsw(ch0 + 1)) + tin] = w1v;
    }
  }
  if (tid < 256) {
    int ch = tid >> 3, j = tid & 7;
    Vt[ch * 352 + 8 * (43 ^ vsw(ch)) + j] = 0;
  }
  __syncthreads();

  int w = tid >> 6, lane = tid & 63, quad = lane >> 4, l16 = lane & 15;
  int qbase = m0 + w * 16;
  int qrow_l = qbase + l16;
  int qc = qrow_l < NTOK ? qrow_l : NTOK - 1;
  s16x8 fq = *(const s16x8*)(qplane + (size_t)qc * 32 + quad * 8);
  const u16* bmrow = b3m + ((size_t)(cls * 3 + head) * 343 + qc) * 352;
  int swl = (l16 ^ (l16 >> 2)) & 3;
  int vsw0 = vsw(l16), vsw1 = vsw(16 + l16);

  float lsum = 0.f;
  f32x4 o0 = {0.f, 0.f, 0.f, 0.f}, o1 = {0.f, 0.f, 0.f, 0.f};
  const f32x4 zz = {0.f, 0.f, 0.f, 0.f};

  for (int t32 = 0; t32 < 11; t32++) {
    #pragma unroll
    for (int h = 0; h < 2; h++) {
      int kb = t32 * 32 + h * 16;
      int ktok = kb + l16;
      s16x8 fk = *(const s16x8*)&Ks[ktok * 32 + 8 * (quad ^ (ktok & 3))];
      f32x4 st = __builtin_amdgcn_mfma_f32_16x16x32_bf16(fk, fq, zz, 0, 0, 0);
      uint2 bm = *(const uint2*)(bmrow + kb + quad * 4);
      float p0 = exp2f(st[0] + bf2f(bm.x & 0xffff));
      float p1 = exp2f(st[1] + bf2f(bm.x >> 16));
      float p2 = exp2f(st[2] + bf2f(bm.y & 0xffff));
      float p3 = exp2f(st[3] + bf2f(bm.y >> 16));
      lsum += (p0 + p1) + (p2 + p3);
      u32 pa = (__float_as_uint(p0) >> 16) | (__float_as_uint(p1) & 0xffff0000u);
      u32 pb = (__float_as_uint(p2) >> 16) | (__float_as_uint(p3) & 0xffff0000u);
      int blkp = h * 2 + (quad >> 1);
      *(uint2*)&Ps[w][l16 * 32 + 8 * (blkp ^ swl) + (quad & 1) * 4] = make_uint2(pa, pb);
    }
    s16x8 fp  = *(const s16x8*)&Ps[w][l16 * 32 + 8 * (quad ^ swl)];
    s16x8 fv0 = *(const s16x8*)&Vt[l16 * 352 + 8 * ((t32 * 4 + quad) ^ vsw0)];
    s16x8 fv1 = *(const s16x8*)&Vt[(16 + l16) * 352 + 8 * ((t32 * 4 + quad) ^ vsw1)];
    o0 = __builtin_amdgcn_mfma_f32_16x16x32_bf16(fp, fv0, o0, 0, 0, 0);
    o1 = __builtin_amdgcn_mfma_f32_16x16x32_bf16(fp, fv1, o1, 0, 0, 0);
  }

  lsum += __shfl_xor(lsum, 16);
  lsum += __shfl_xor(lsum, 32);
  #pragma unroll
  for (int r = 0; r < 4; r++) {
    int qrow = qbase + quad * 4 + r;
    float ls = __shfl(lsum, quad * 4 + r);
    if (qrow < NTOK) {
      float rs = 1.0f / ls;
      size_t ob = (wbase + qrow) * 96 + head * 32;
      attnb[ob + l16] = f2bf(o0[r] * rs);
      attnb[ob + 16 + l16] = f2bf(o1[r] * rs);
    }
  }
}

// ---------------- mega-fused MLP with register-prefetch weight pipeline ----------------
// grid = 686 (64 rows/block), block = 256 (4 waves x 16 rows).
struct PF { uint4 v[5]; };
__device__ __forceinline__ void pf_load(PF& p, const u16* base, int rowstride, int coloff, int tid) {
  #pragma unroll
  for (int t = 0; t < 5; t++) {
    int idx = tid + t * 256;
    if (idx < 1152) {
      int row = idx / 12, cc = (idx - row * 12) * 8;
      p.v[t] = *(const uint4*)(base + (size_t)row * rowstride + coloff + cc);
    }
  }
}
__device__ __forceinline__ void pf_commit(const PF& p, u16* Ws, int tid) {
  #pragma unroll
  for (int t = 0; t < 5; t++) {
    int idx = tid + t * 256;
    if (idx < 1152) {
      int row = idx / 12, cc = (idx - row * 12) * 8;
      *(uint4*)&Ws[row * 104 + cc] = p.v[t];
    }
  }
}

__global__ __launch_bounds__(256) void mlp_fused_kernel(
    const u16* __restrict__ attnb, const u16* __restrict__ wcat,
    const void* __restrict__ x, const void* __restrict__ b_proj,
    const void* __restrict__ g2, const void* __restrict__ b2,
    const void* __restrict__ b_fc1, const void* __restrict__ b_fc2,
    void* __restrict__ outp) {
  int f32 = detect_f32x((const u16*)x);
  __shared__ alignas(16) u16 As[64 * 104];
  __shared__ alignas(16) u16 As2[64 * 104];
  __shared__ alignas(16) u16 Ws[96 * 104];
  const u16* w_projb = wcat + 27648;
  const u16* w_fc1b  = wcat + 36864;
  const u16* w_fc2b  = wcat + 73728;
  int tid = threadIdx.x, m0 = blockIdx.x * 64;
  int w = tid >> 6, lane = tid & 63, quad = lane >> 4, l16 = lane & 15;

  PF p;
  pf_load(p, w_projb, 96, 0, tid);                 // prefetch proj
  for (int i = tid; i < 768; i += 256) {           // stage attn rows
    int row = i / 12, c = (i - row * 12) * 8;
    *(uint4*)&As[row * 104 + c] = *(const uint4*)(attnb + (size_t)(m0 + row) * 96 + c);
  }
  __syncthreads();
  pf_commit(p, Ws, tid);                           // proj -> LDS
  pf_load(p, w_fc1b, 96, 0, tid);                  // prefetch fc1_0
  __syncthreads();

  f32x4 accp[6];
  #pragma unroll
  for (int j = 0; j < 6; j++) accp[j] = (f32x4){0.f, 0.f, 0.f, 0.f};
  #pragma unroll
  for (int kc = 0; kc < 3; kc++) {
    s16x8 fa = *(const s16x8*)&As[(w * 16 + l16) * 104 + kc * 32 + quad * 8];
    #pragma unroll
    for (int j = 0; j < 6; j++) {
      s16x8 fb = *(const s16x8*)&Ws[(j * 16 + l16) * 104 + kc * 32 + quad * 8];
      accp[j] = __builtin_amdgcn_mfma_f32_16x16x32_bf16(fa, fb, accp[j], 0, 0, 0);
    }
  }

  // epilogue 1: + b_proj + x -> rv ; LN2 -> As (wave-private rows, no extra barrier)
  float bp[6], gv[6], b2v[6];
  #pragma unroll
  for (int j = 0; j < 6; j++) {
    int nn = j * 16 + l16;
    bp[j] = ldf(b_proj, f32, nn); gv[j] = ldf(g2, f32, nn); b2v[j] = ldf(b2, f32, nn);
  }
  float rv[4][6];
  size_t sb[4];
  #pragma unroll
  for (int r = 0; r < 4; r++) {
    int mm = m0 + w * 16 + quad * 4 + r;
    sb[r] = spatial_base(mm);
    float s = 0.f, ss = 0.f;
    #pragma unroll
    for (int j = 0; j < 6; j++) {
      float v = accp[j][r] + bp[j] + ldf(x, f32, sb[r] + j * 16 + l16);
      rv[r][j] = v; s += v; ss += v * v;
    }
    #pragma unroll
    for (int o = 1; o < 16; o <<= 1) { s += __shfl_xor(s, o); ss += __shfl_xor(ss, o); }
    float mean = s * (1.f / 96.f);
    float var = ss * (1.f / 96.f) - mean * mean;
    float rstd = rsqrtf(var + 1e-5f);
    #pragma unroll
    for (int j = 0; j < 6; j++)
      As[(w * 16 + quad * 4 + r) * 104 + j * 16 + l16] = f2bf((rv[r][j] - mean) * rstd * gv[j] + b2v[j]);
  }

  f32x4 acc2[6];
  #pragma unroll
  for (int j = 0; j < 6; j++) acc2[j] = (f32x4){0.f, 0.f, 0.f, 0.f};
  for (int c = 0; c < 4; c++) {
    __syncthreads();                       // all waves done reading Ws(prev)
    pf_commit(p, Ws, tid);                 // fc1_c -> LDS
    pf_load(p, w_fc2b, 384, 96 * c, tid);  // prefetch fc2_c
    __syncthreads();
    f32x4 a1[6];
    #pragma unroll
    for (int j = 0; j < 6; j++) a1[j] = (f32x4){0.f, 0.f, 0.f, 0.f};
    #pragma unroll
    for (int kc = 0; kc < 3; kc++) {
      s16x8 fa = *(const s16x8*)&As[(w * 16 + l16) * 104 + kc * 32 + quad * 8];
      #pragma unroll
      for (int j = 0; j < 6; j++) {
        s16x8 fb = *(const s16x8*)&Ws[(j * 16 + l16) * 104 + kc * 32 + quad * 8];
        a1[j] = __builtin_amdgcn_mfma_f32_16x16x32_bf16(fa, fb, a1[j], 0, 0, 0);
      }
    }
    #pragma unroll
    for (int j = 0; j < 6; j++) {
      float bf1 = ldf(b_fc1, f32, 96 * c + j * 16 + l16);
      #pragma unroll
      for (int r = 0; r < 4; r++) {
        float v = a1[j][r] + bf1;
        v = 0.5f * v * (1.0f + erff(v * 0.70710678118f));
        As2[(w * 16 + quad * 4 + r) * 104 + j * 16 + l16] = f2bf(v);
      }
    }
    __syncthreads();                       // all waves done reading Ws(fc1_c)
    pf_commit(p, Ws, tid);                 // fc2_c -> LDS
    if (c < 3) pf_load(p, w_fc1b + (size_t)96 * (c + 1) * 96, 96, 0, tid);  // prefetch fc1_{c+1}
    __syncthreads();
    #pragma unroll
    for (int kc = 0; kc < 3; kc++) {
      s16x8 fa2 = *(const s16x8*)&As2[(w * 16 + l16) * 104 + kc * 32 + quad * 8];
      #pragma unroll
      for (int j = 0; j < 6; j++) {
        s16x8 fb = *(const s16x8*)&Ws[(j * 16 + l16) * 104 + kc * 32 + quad * 8];
        acc2[j] = __builtin_amdgcn_mfma_f32_16x16x32_bf16(fa2, fb, acc2[j], 0, 0, 0);
      }
    }
  }
  // final: + b_fc2 + rv -> out at spatial location (output dtype = input dtype)
  float bf2v[6];
  #pragma unroll
  for (int j = 0; j < 6; j++) bf2v[j] = ldf(b_fc2, f32, j * 16 + l16);
  #pragma unroll
  for (int r = 0; r < 4; r++) {
    #pragma unroll
    for (int j = 0; j < 6; j++) {
      float v = acc2[j][r] + bf2v[j] + rv[r][j];
      if (f32) ((float*)outp)[sb[r] + j * 16 + l16] = v;
      else     ((u16*)outp)[sb[r] + j * 16 + l16] = f2bf(v);
    }
  }
}

extern "C" void kernel_launch(void* const* d_in, const int* in_sizes, int n_in,
                              void* d_out, int out_size, void* d_ws, size_t ws_size,
                              hipStream_t stream) {
  (void)in_sizes; (void)n_in; (void)out_size; (void)ws_size;
  const void* x       = d_in[0];
  const void* g1      = d_in[2];
  const void* b1      = d_in[3];
  const void* w_qkv   = d_in[4];
  const void* b_qkv   = d_in[5];
  const void* bias_tb = d_in[6];
  const void* w_proj  = d_in[7];
  const void* b_proj  = d_in[8];
  const void* g2      = d_in[9];
  const void* b2      = d_in[10];
  const void* w_fc1   = d_in[11];
  const void* b_fc1   = d_in[12];
  const void* w_fc2   = d_in[13];
  const void* b_fc2   = d_in[14];
  const int* rel_idx  = (const int*)d_in[15];

  // workspace (~39.7 MB): qkvb 25.3M | attnb 8.43M | b3m 5.80M | wcat 0.22M
  char* ws = (char*)d_ws;
  u16*  qkvb  = (u16*)(ws + 256);
  u16*  attnb = (u16*)(ws + 256 + 25288704);
  u16*  b3mb  = (u16*)(ws + 256 + 25288704 + 8429568);
  u16*  wcat  = (u16*)(ws + 256 + 25288704 + 8429568 + 5795328);
  u16*  w_qkvb = wcat;

  // 1. setup: weight conversion (blocks 0..431) + B3M bias/mask table (blocks 432..774)
  setup_kernel<<<775, 256, 0, stream>>>((const u16*)x, w_qkv, w_proj, w_fc1, w_fc2,
                                        bias_tb, rel_idx, wcat, b3mb);
  // 2. LN1 + shift/partition + QKV GEMM -> planar qkv (q pre-scaled by log2e/sqrt(32))
  qkv_ln_kernel<<<dim3(343, 3), 256, 0, stream>>>(x, g1, b1, w_qkvb, b_qkv, qkvb);
  // 3. flash attention -> attnb
  attn_mfma_kernel<<<dim3(3, 384), 512, 0, stream>>>(qkvb, b3mb, attnb);
  // 4. proj + residual + LN2 + FC1 + GELU + FC2 + residual + scatter -> d_out
  mlp_fused_kernel<<<686, 256, 0, stream>>>(attnb, wcat, x, b_proj, g2, b2,
                                            b_fc1, b_fc2, d_out);
}

// Round 10
// 238.218 us; speedup vs baseline: 1.2318x; 1.2318x over previous
//
#include <hip/hip_runtime.h>
#include <hip/hip_bf16.h>
#include <math.h>

typedef unsigned short u16;
typedef unsigned int u32;
typedef unsigned char u8;

#define T_TOK 43904   // 128 windows * 343 tokens
#define NTOK 343
#define LOG2E 1.4426950408889634f
#define MASKV 144.26950408889634f   // 100 * log2(e)

typedef __attribute__((ext_vector_type(4))) float f32x4;
typedef __attribute__((ext_vector_type(8))) short s16x8;

__device__ __forceinline__ float bf2f(u32 v) { return __uint_as_float(v << 16); }
__device__ __forceinline__ u16 f2bf(float f) {
  u32 u = __float_as_uint(f);
  return (u16)((u + 0x7fffu + ((u >> 16) & 1u)) >> 16);
}

// ---- dual-dtype helpers: f32!=0 -> buffer is fp32, else packed bf16 ----
__device__ __forceinline__ float ldf(const void* p, int f32, size_t i) {
  return f32 ? ((const float*)p)[i] : bf2f(((const u16*)p)[i]);
}
__device__ __forceinline__ void ld8(const void* p, int f32, size_t i, float* o) {  // i%8==0
  if (f32) {
    float4 a = *(const float4*)((const float*)p + i);
    float4 b = *(const float4*)((const float*)p + i + 4);
    o[0] = a.x; o[1] = a.y; o[2] = a.z; o[3] = a.w;
    o[4] = b.x; o[5] = b.y; o[6] = b.z; o[7] = b.w;
  } else {
    uint4 pk = *(const uint4*)((const u16*)p + i);
    u32 v[4] = {pk.x, pk.y, pk.z, pk.w};
    #pragma unroll
    for (int q = 0; q < 4; q++) { o[2 * q] = bf2f(v[q] & 0xffff); o[2 * q + 1] = bf2f(v[q] >> 16); }
  }
}

// per-block dtype detection: bf16 N(0,1) never has exponent>=0x90 in its u16s;
// fp32 low mantissa halves do ~44% of the time. 512 samples -> certain.
__device__ __forceinline__ int detect_f32x(const u16* xr) {
  int lane = threadIdx.x & 63;
  int bad = 0;
  #pragma unroll
  for (int q = 0; q < 8; q++) {
    u16 b = xr[(lane * 8 + q) * 2];
    if (((b >> 7) & 0xff) >= 0x90) bad = 1;
  }
  return (__ballot(bad) != 0ull) ? 1 : 0;
}

// token index t (window-major) -> element offset of the (b,d,h,w) voxel in x/out
__device__ __forceinline__ size_t spatial_base(int t) {
  int win = t / 343, n = t - win * 343;
  int bb = win >> 6, wrem = win & 63;
  int wd = wrem >> 4, wh = (wrem >> 2) & 3, ww = wrem & 3;
  int td = n / 49; int r = n - td * 49; int th = r / 7; int tw = r - th * 7;
  int d0 = wd * 7 + td + 3; if (d0 >= 28) d0 -= 28;
  int h0 = wh * 7 + th + 3; if (h0 >= 28) h0 -= 28;
  int w0 = ww * 7 + tw + 3; if (w0 >= 28) w0 -= 28;
  return (size_t)(((bb * 28 + d0) * 28 + h0) * 28 + w0) * 96;
}

// shifted-window mask region id (exact reproduction of MONAI compute_mask)
__device__ __forceinline__ int zone3(int p) { return p < 21 ? 0 : (p < 25 ? 1 : 2); }
__device__ __forceinline__ int cid_of(int mw, int n) {
  int td = n / 49, rr = n - td * 49, th = rr / 7, tw = rr - th * 7;
  int d = (mw >> 4) * 7 + td, h = ((mw >> 2) & 3) * 7 + th, w = (mw & 3) * 7 + tw;
  return zone3(d) * 9 + zone3(h) * 3 + zone3(w);
}

// ---------------- setup: weight conversion + B3M expansion ----------------
__global__ __launch_bounds__(256) void setup_kernel(
    const u16* __restrict__ x,
    const void* __restrict__ w0, const void* __restrict__ w1,
    const void* __restrict__ w2, const void* __restrict__ w3,
    const void* __restrict__ bias_table, const int* __restrict__ rel,
    u16* __restrict__ wcat, u16* __restrict__ b3m) {
  int f32 = detect_f32x(x);
  int b = blockIdx.x;
  if (b < 432) {
    int g = b * 256 + threadIdx.x;
    if (g < 110592) {
      float v;
      if (g < 27648)      v = ldf(w0, f32, g);
      else if (g < 36864) v = ldf(w1, f32, g - 27648);
      else if (g < 73728) v = ldf(w2, f32, g - 36864);
      else                v = ldf(w3, f32, g - 73728);
      wcat[g] = f2bf(v);
    }
    return;
  }
  int row = b - 432;   // 0..342
  for (int by = 0; by < 24; by++) {
    int cls = by / 3, head = by - cls * 3;
    int mw = ((cls & 4) ? 48 : 0) | ((cls & 2) ? 12 : 0) | ((cls & 1) ? 3 : 0);
    int cidq = cid_of(mw, row);
    for (int col = threadIdx.x; col < 352; col += 256) {
      float v = -MASKV;
      if (col < 343) {
        v = ldf(bias_table, f32, (size_t)rel[row * 343 + col] * 3 + head) * LOG2E;
        if (cid_of(mw, col) != cidq) v -= MASKV;
      }
      b3m[((size_t)by * 343 + row) * 352 + col] = f2bf(v);
    }
  }
}

// ---------------- fused LN1 + QKV GEMM -> planar [sel*3+head][tok][32] ----------------
__global__ __launch_bounds__(256) void qkv_ln_kernel(
    const void* __restrict__ x, const void* __restrict__ g1, const void* __restrict__ b1,
    const u16* __restrict__ Wb, const void* __restrict__ bias,
    u16* __restrict__ outp) {
  int f32 = detect_f32x((const u16*)x);
  __shared__ alignas(16) u16 As[128 * 104];
  __shared__ alignas(16) u16 Ws[96 * 104];
  __shared__ float gld[96], bld[96];
  int tid = threadIdx.x;
  int m0 = blockIdx.x * 128, n0 = blockIdx.y * 96;
  int w = tid >> 6, lane = tid & 63, quad = lane >> 4, l16 = lane & 15;

  for (int i = tid; i < 1536; i += 256) {
    int row = i / 12, cc = (i - row * 12) * 8;
    size_t sb = spatial_base(m0 + row);
    float f[8];
    ld8(x, f32, sb + cc, f);
    uint4 pk;
    pk.x = (u32)f2bf(f[0]) | ((u32)f2bf(f[1]) << 16);
    pk.y = (u32)f2bf(f[2]) | ((u32)f2bf(f[3]) << 16);
    pk.z = (u32)f2bf(f[4]) | ((u32)f2bf(f[5]) << 16);
    pk.w = (u32)f2bf(f[6]) | ((u32)f2bf(f[7]) << 16);
    *(uint4*)&As[row * 104 + cc] = pk;
  }
  for (int i = tid; i < 1152; i += 256) {
    int row = i / 12, cc = (i - row * 12) * 8;
    *(uint4*)&Ws[row * 104 + cc] = *(const uint4*)(Wb + (size_t)(n0 + row) * 96 + cc);
  }
  if (tid < 96) { gld[tid] = ldf(g1, f32, tid); bld[tid] = ldf(b1, f32, tid); }
  __syncthreads();

  // LN in place: 2 threads per row
  {
    int row = tid >> 1, half = tid & 1;
    u32* rp = (u32*)&As[row * 104] + half * 24;
    float s = 0.f, ss = 0.f;
    #pragma unroll
    for (int m = 0; m < 24; m++) {
      u32 pk = rp[m];
      float a = bf2f(pk & 0xffff), b = bf2f(pk >> 16);
      s += a + b; ss += a * a + b * b;
    }
    s += __shfl_xor(s, 1); ss += __shfl_xor(ss, 1);
    float mean = s * (1.f / 96.f);
    float var = ss * (1.f / 96.f) - mean * mean;
    float rstd = rsqrtf(var + 1e-5f);
    int cbase = half * 48;
    #pragma unroll
    for (int m = 0; m < 24; m++) {
      u32 pk = rp[m];
      float a = bf2f(pk & 0xffff), b = bf2f(pk >> 16);
      a = (a - mean) * rstd * gld[cbase + 2 * m] + bld[cbase + 2 * m];
      b = (b - mean) * rstd * gld[cbase + 2 * m + 1] + bld[cbase + 2 * m + 1];
      rp[m] = (u32)f2bf(a) | ((u32)f2bf(b) << 16);
    }
  }
  __syncthreads();

  f32x4 acc[2][6];
  #pragma unroll
  for (int i = 0; i < 2; i++)
    #pragma unroll
    for (int j = 0; j < 6; j++) acc[i][j] = (f32x4){0.f, 0.f, 0.f, 0.f};
  #pragma unroll
  for (int kc = 0; kc < 3; kc++) {
    s16x8 fa0 = *(const s16x8*)&As[(w * 32 + l16) * 104 + kc * 32 + quad * 8];
    s16x8 fa1 = *(const s16x8*)&As[(w * 32 + 16 + l16) * 104 + kc * 32 + quad * 8];
    #pragma unroll
    for (int j = 0; j < 6; j++) {
      s16x8 fb = *(const s16x8*)&Ws[(j * 16 + l16) * 104 + kc * 32 + quad * 8];
      acc[0][j] = __builtin_amdgcn_mfma_f32_16x16x32_bf16(fa0, fb, acc[0][j], 0, 0, 0);
      acc[1][j] = __builtin_amdgcn_mfma_f32_16x16x32_bf16(fa1, fb, acc[1][j], 0, 0, 0);
    }
  }
  #pragma unroll
  for (int i = 0; i < 2; i++) {
    #pragma unroll
    for (int r = 0; r < 4; r++) {
      int mm = m0 + w * 32 + i * 16 + quad * 4 + r;
      #pragma unroll
      for (int j = 0; j < 6; j++) {
        int nn = n0 + j * 16 + l16;
        float v = acc[i][j][r] + ldf(bias, f32, nn);
        int sel = nn / 96, hd = (nn - sel * 96) >> 5, cc = nn & 31;
        float scl = (sel == 0) ? 0.25504208f : 1.0f;   // log2e / sqrt(32)
        outp[((size_t)(sel * 3 + hd) * T_TOK + mm) * 32 + cc] = f2bf(v * scl);
      }
    }
  }
}

// ---------------- MFMA flash attention ----------------
__device__ __forceinline__ int vsw(int ch) { return ((ch >> 1) ^ (ch >> 3)) & 3; }

__global__ __launch_bounds__(512) void attn_mfma_kernel(
    const u16* __restrict__ qkv, const u16* __restrict__ b3m,
    u16* __restrict__ attnb) {
  __shared__ alignas(16) u16 Ks[352 * 32];
  __shared__ alignas(16) u16 Vt[32 * 352];
  __shared__ alignas(16) u16 Ps[8][512];

  int tid = threadIdx.x;
  int wh = blockIdx.y;
  int head = wh % 3;
  int win = wh / 3;
  int mw = win & 63;
  int cls = (((mw >> 4) == 3) ? 4 : 0) | ((((mw >> 2) & 3) == 3) ? 2 : 0) | (((mw & 3) == 3) ? 1 : 0);
  int m0 = blockIdx.x * 128;
  size_t wbase = (size_t)win * NTOK;

  const u16* qplane = qkv + ((size_t)head * T_TOK + wbase) * 32;
  const u16* kplane = qkv + ((size_t)(3 + head) * T_TOK + wbase) * 32;
  const u16* vplane = qkv + ((size_t)(6 + head) * T_TOK + wbase) * 32;

  for (int i = tid; i < 1408; i += 512) {
    int tok = i >> 2, cb = i & 3;
    uint4 kv = make_uint4(0, 0, 0, 0);
    if (tok < 343) kv = *(const uint4*)(kplane + (size_t)tok * 32 + cb * 8);
    *(uint4*)&Ks[tok * 32 + 8 * (cb ^ (tok & 3))] = kv;
  }
  for (int i = tid; i < 688; i += 512) {
    int p = i >> 2, cb = (i & 3) * 8;
    int t0 = 2 * p;
    uint4 v0 = *(const uint4*)(vplane + (size_t)t0 * 32 + cb);
    uint4 v1 = make_uint4(0, 0, 0, 0);
    if (t0 + 1 < 343) v1 = *(const uint4*)(vplane + (size_t)(t0 + 1) * 32 + cb);
    u32 a0[4] = {v0.x, v0.y, v0.z, v0.w};
    u32 a1[4] = {v1.x, v1.y, v1.z, v1.w};
    int blk = t0 >> 3, tin = (t0 & 7) >> 1;
    #pragma unroll
    for (int q = 0; q < 4; q++) {
      int ch0 = cb + 2 * q;
      u32 w0v = (a0[q] & 0xffffu) | ((a1[q] & 0xffffu) << 16);
      u32 w1v = (a0[q] >> 16) | (a1[q] & 0xffff0000u);
      ((u32*)Vt)[ch0 * 176 + 4 * (blk ^ vsw(ch0)) + tin] = w0v;
      ((u32*)Vt)[(ch0 + 1) * 176 + 4 * (blk ^ vsw(ch0 + 1)) + tin] = w1v;
    }
  }
  if (tid < 256) {
    int ch = tid >> 3, j = tid & 7;
    Vt[ch * 352 + 8 * (43 ^ vsw(ch)) + j] = 0;
  }
  __syncthreads();

  int w = tid >> 6, lane = tid & 63, quad = lane >> 4, l16 = lane & 15;
  int qbase = m0 + w * 16;
  int qrow_l = qbase + l16;
  int qc = qrow_l < NTOK ? qrow_l : NTOK - 1;
  s16x8 fq = *(const s16x8*)(qplane + (size_t)qc * 32 + quad * 8);
  const u16* bmrow = b3m + ((size_t)(cls * 3 + head) * 343 + qc) * 352;
  int swl = (l16 ^ (l16 >> 2)) & 3;
  int vsw0 = vsw(l16), vsw1 = vsw(16 + l16);

  float lsum = 0.f;
  f32x4 o0 = {0.f, 0.f, 0.f, 0.f}, o1 = {0.f, 0.f, 0.f, 0.f};
  const f32x4 zz = {0.f, 0.f, 0.f, 0.f};

  for (int t32 = 0; t32 < 11; t32++) {
    #pragma unroll
    for (int h = 0; h < 2; h++) {
      int kb = t32 * 32 + h * 16;
      int ktok = kb + l16;
      s16x8 fk = *(const s16x8*)&Ks[ktok * 32 + 8 * (quad ^ (ktok & 3))];
      f32x4 st = __builtin_amdgcn_mfma_f32_16x16x32_bf16(fk, fq, zz, 0, 0, 0);
      uint2 bm = *(const uint2*)(bmrow + kb + quad * 4);
      float p0 = exp2f(st[0] + bf2f(bm.x & 0xffff));
      float p1 = exp2f(st[1] + bf2f(bm.x >> 16));
      float p2 = exp2f(st[2] + bf2f(bm.y & 0xffff));
      float p3 = exp2f(st[3] + bf2f(bm.y >> 16));
      lsum += (p0 + p1) + (p2 + p3);
      u32 pa = (__float_as_uint(p0) >> 16) | (__float_as_uint(p1) & 0xffff0000u);
      u32 pb = (__float_as_uint(p2) >> 16) | (__float_as_uint(p3) & 0xffff0000u);
      int blkp = h * 2 + (quad >> 1);
      *(uint2*)&Ps[w][l16 * 32 + 8 * (blkp ^ swl) + (quad & 1) * 4] = make_uint2(pa, pb);
    }
    s16x8 fp  = *(const s16x8*)&Ps[w][l16 * 32 + 8 * (quad ^ swl)];
    s16x8 fv0 = *(const s16x8*)&Vt[l16 * 352 + 8 * ((t32 * 4 + quad) ^ vsw0)];
    s16x8 fv1 = *(const s16x8*)&Vt[(16 + l16) * 352 + 8 * ((t32 * 4 + quad) ^ vsw1)];
    o0 = __builtin_amdgcn_mfma_f32_16x16x32_bf16(fp, fv0, o0, 0, 0, 0);
    o1 = __builtin_amdgcn_mfma_f32_16x16x32_bf16(fp, fv1, o1, 0, 0, 0);
  }

  lsum += __shfl_xor(lsum, 16);
  lsum += __shfl_xor(lsum, 32);
  #pragma unroll
  for (int r = 0; r < 4; r++) {
    int qrow = qbase + quad * 4 + r;
    float ls = __shfl(lsum, quad * 4 + r);
    if (qrow < NTOK) {
      float rs = 1.0f / ls;
      size_t ob = (wbase + qrow) * 96 + head * 32;
      attnb[ob + l16] = f2bf(o0[r] * rs);
      attnb[ob + 16 + l16] = f2bf(o1[r] * rs);
    }
  }
}

// ---------------- mega-fused MLP (round-8 structure: no register prefetch) ----------------
// grid = 686 (64 rows/block), block = 256 (4 waves x 16 rows).
__global__ __launch_bounds__(256) void mlp_fused_kernel(
    const u16* __restrict__ attnb, const u16* __restrict__ wcat,
    const void* __restrict__ x, const void* __restrict__ b_proj,
    const void* __restrict__ g2, const void* __restrict__ b2,
    const void* __restrict__ b_fc1, const void* __restrict__ b_fc2,
    void* __restrict__ outp) {
  int f32 = detect_f32x((const u16*)x);
  __shared__ alignas(16) u16 As[64 * 104];
  __shared__ alignas(16) u16 As2[64 * 104];
  __shared__ alignas(16) u16 Ws[96 * 104];
  const u16* w_projb = wcat + 27648;
  const u16* w_fc1b  = wcat + 36864;
  const u16* w_fc2b  = wcat + 73728;
  int tid = threadIdx.x, m0 = blockIdx.x * 64;
  int w = tid >> 6, lane = tid & 63, quad = lane >> 4, l16 = lane & 15;

  for (int i = tid; i < 768; i += 256) {
    int row = i / 12, c = (i - row * 12) * 8;
    *(uint4*)&As[row * 104 + c] = *(const uint4*)(attnb + (size_t)(m0 + row) * 96 + c);
  }
  for (int i = tid; i < 1152; i += 256) {
    int row = i / 12, c = (i - row * 12) * 8;
    *(uint4*)&Ws[row * 104 + c] = *(const uint4*)(w_projb + row * 96 + c);
  }
  __syncthreads();
  f32x4 accp[6];
  #pragma unroll
  for (int j = 0; j < 6; j++) accp[j] = (f32x4){0.f, 0.f, 0.f, 0.f};
  #pragma unroll
  for (int kc = 0; kc < 3; kc++) {
    s16x8 fa = *(const s16x8*)&As[(w * 16 + l16) * 104 + kc * 32 + quad * 8];
    #pragma unroll
    for (int j = 0; j < 6; j++) {
      s16x8 fb = *(const s16x8*)&Ws[(j * 16 + l16) * 104 + kc * 32 + quad * 8];
      accp[j] = __builtin_amdgcn_mfma_f32_16x16x32_bf16(fa, fb, accp[j], 0, 0, 0);
    }
  }
  __syncthreads();   // all waves done reading As/Ws before overwrite

  // epilogue 1: + b_proj + x -> rv ; LN2 -> As
  float bp[6], gv[6], b2v[6];
  #pragma unroll
  for (int j = 0; j < 6; j++) {
    int nn = j * 16 + l16;
    bp[j] = ldf(b_proj, f32, nn); gv[j] = ldf(g2, f32, nn); b2v[j] = ldf(b2, f32, nn);
  }
  float rv[4][6];
  size_t sb[4];
  #pragma unroll
  for (int r = 0; r < 4; r++) {
    int mm = m0 + w * 16 + quad * 4 + r;
    sb[r] = spatial_base(mm);
    float s = 0.f, ss = 0.f;
    #pragma unroll
    for (int j = 0; j < 6; j++) {
      float v = accp[j][r] + bp[j] + ldf(x, f32, sb[r] + j * 16 + l16);
      rv[r][j] = v; s += v; ss += v * v;
    }
    #pragma unroll
    for (int o = 1; o < 16; o <<= 1) { s += __shfl_xor(s, o); ss += __shfl_xor(ss, o); }
    float mean = s * (1.f / 96.f);
    float var = ss * (1.f / 96.f) - mean * mean;
    float rstd = rsqrtf(var + 1e-5f);
    #pragma unroll
    for (int j = 0; j < 6; j++)
      As[(w * 16 + quad * 4 + r) * 104 + j * 16 + l16] = f2bf((rv[r][j] - mean) * rstd * gv[j] + b2v[j]);
  }

  f32x4 acc2[6];
  #pragma unroll
  for (int j = 0; j < 6; j++) acc2[j] = (f32x4){0.f, 0.f, 0.f, 0.f};
  for (int c = 0; c < 4; c++) {
    __syncthreads();
    for (int i = tid; i < 1152; i += 256) {
      int row = i / 12, cc = (i - row * 12) * 8;
      *(uint4*)&Ws[row * 104 + cc] = *(const uint4*)(w_fc1b + (size_t)(96 * c + row) * 96 + cc);
    }
    __syncthreads();
    f32x4 a1[6];
    #pragma unroll
    for (int j = 0; j < 6; j++) a1[j] = (f32x4){0.f, 0.f, 0.f, 0.f};
    #pragma unroll
    for (int kc = 0; kc < 3; kc++) {
      s16x8 fa = *(const s16x8*)&As[(w * 16 + l16) * 104 + kc * 32 + quad * 8];
      #pragma unroll
      for (int j = 0; j < 6; j++) {
        s16x8 fb = *(const s16x8*)&Ws[(j * 16 + l16) * 104 + kc * 32 + quad * 8];
        a1[j] = __builtin_amdgcn_mfma_f32_16x16x32_bf16(fa, fb, a1[j], 0, 0, 0);
      }
    }
    #pragma unroll
    for (int j = 0; j < 6; j++) {
      float bf1 = ldf(b_fc1, f32, 96 * c + j * 16 + l16);
      #pragma unroll
      for (int r = 0; r < 4; r++) {
        float v = a1[j][r] + bf1;
        v = 0.5f * v * (1.0f + erff(v * 0.70710678118f));
        As2[(w * 16 + quad * 4 + r) * 104 + j * 16 + l16] = f2bf(v);
      }
    }
    __syncthreads();
    for (int i = tid; i < 1152; i += 256) {
      int row = i / 12, cc = (i - row * 12) * 8;
      *(uint4*)&Ws[row * 104 + cc] = *(const uint4*)(w_fc2b + (size_t)row * 384 + 96 * c + cc);
    }
    __syncthreads();
    #pragma unroll
    for (int kc = 0; kc < 3; kc++) {
      s16x8 fa2 = *(const s16x8*)&As2[(w * 16 + l16) * 104 + kc * 32 + quad * 8];
      #pragma unroll
      for (int j = 0; j < 6; j++) {
        s16x8 fb = *(const s16x8*)&Ws[(j * 16 + l16) * 104 + kc * 32 + quad * 8];
        acc2[j] = __builtin_amdgcn_mfma_f32_16x16x32_bf16(fa2, fb, acc2[j], 0, 0, 0);
      }
    }
  }
  // final: + b_fc2 + rv -> out at spatial location (output dtype = input dtype)
  float bf2v[6];
  #pragma unroll
  for (int j = 0; j < 6; j++) bf2v[j] = ldf(b_fc2, f32, j * 16 + l16);
  #pragma unroll
  for (int r = 0; r < 4; r++) {
    #pragma unroll
    for (int j = 0; j < 6; j++) {
      float v = acc2[j][r] + bf2v[j] + rv[r][j];
      if (f32) ((float*)outp)[sb[r] + j * 16 + l16] = v;
      else     ((u16*)outp)[sb[r] + j * 16 + l16] = f2bf(v);
    }
  }
}

extern "C" void kernel_launch(void* const* d_in, const int* in_sizes, int n_in,
                              void* d_out, int out_size, void* d_ws, size_t ws_size,
                              hipStream_t stream) {
  (void)in_sizes; (void)n_in; (void)out_size; (void)ws_size;
  const void* x       = d_in[0];
  const void* g1      = d_in[2];
  const void* b1      = d_in[3];
  const void* w_qkv   = d_in[4];
  const void* b_qkv   = d_in[5];
  const void* bias_tb = d_in[6];
  const void* w_proj  = d_in[7];
  const void* b_proj  = d_in[8];
  const void* g2      = d_in[9];
  const void* b2      = d_in[10];
  const void* w_fc1   = d_in[11];
  const void* b_fc1   = d_in[12];
  const void* w_fc2   = d_in[13];
  const void* b_fc2   = d_in[14];
  const int* rel_idx  = (const int*)d_in[15];

  // workspace (~39.7 MB): qkvb 25.3M | attnb 8.43M | b3m 5.80M | wcat 0.22M
  char* ws = (char*)d_ws;
  u16*  qkvb  = (u16*)(ws + 256);
  u16*  attnb = (u16*)(ws + 256 + 25288704);
  u16*  b3mb  = (u16*)(ws + 256 + 25288704 + 8429568);
  u16*  wcat  = (u16*)(ws + 256 + 25288704 + 8429568 + 5795328);
  u16*  w_qkvb = wcat;

  // 1. setup: weight conversion (blocks 0..431) + B3M bias/mask table (blocks 432..774)
  setup_kernel<<<775, 256, 0, stream>>>((const u16*)x, w_qkv, w_proj, w_fc1, w_fc2,
                                        bias_tb, rel_idx, wcat, b3mb);
  // 2. LN1 + shift/partition + QKV GEMM -> planar qkv (q pre-scaled by log2e/sqrt(32))
  qkv_ln_kernel<<<dim3(343, 3), 256, 0, stream>>>(x, g1, b1, w_qkvb, b_qkv, qkvb);
  // 3. flash attention -> attnb
  attn_mfma_kernel<<<dim3(3, 384), 512, 0, stream>>>(qkvb, b3mb, attnb);
  // 4. proj + residual + LN2 + FC1 + GELU + FC2 + residual + scatter -> d_out
  mlp_fused_kernel<<<686, 256, 0, stream>>>(attnb, wcat, x, b_proj, g2, b2,
                                            b_fc1, b_fc2, d_out);
}